// Round 24
// baseline (28.938 us; speedup 1.0000x reference)
//
#include <hip/hip_runtime.h>
#include <math.h>

#define N 2048
#define D 48
#define K 16
#define TILE 32
#define NT (N / TILE)              // 64 tiles per dimension
#define NBLK (NT * (NT + 1) / 2)   // 2080 upper-triangular tiles
#define ST 36                      // mirror-transpose row stride (2-way max alias)

// FROZEN numerics contract (validated r18, absmax = 1 bf16 ulp):
//   s = (q0 + q2) + q1   (plain, pinned)  — XLA SLP horizontal tree
//   g = fma(x2,y2, fma(x1,y1, fl(x0*y0))) — Eigen-FMA ascending chain
//   t1 = fl(s_n + s_m); d2 = fmaf(-2,g,t1); dist = sqrt(fmax(d2,0))
//   ip = fl(1-dist); den = fl(1 - fl(t2*ip))
// r23 lesson: ~25us invariant under staging/LDS-read changes => phases
// serialize (lockstep barriers, low block diversity). This round: 1-wave
// blocks (no lockstep), K split in halves (8KB LDS -> 20 blocks/CU),
// 16 pairs/lane ILP, 0.5 ds_reads/pair.

__global__ __launch_bounds__(64, 4)
void volt_tri(const float* __restrict__ vct, const float* __restrict__ posnum,
              float* __restrict__ out) {
#pragma clang fp contract(off)
    __shared__ float4 SB[2 * 8 * TILE];           // 8 KB: one k-half, both sets
    float* T = reinterpret_cast<float*>(SB);      // mirror transpose reuse

    const int lane = threadIdx.x;

    // decode upper-triangular tile (by <= bx)
    int t = blockIdx.x;
    int by = 0;
    while ((by + 1) * NT - ((by + 1) * by) / 2 <= t) ++by;
    const int bx = by + (t - (by * NT - (by * (by - 1)) / 2));
    const int row0 = by * TILE, col0 = bx * TILE;

    const float tau = posnum[0];
    const float lam = posnum[1];
    const float t2 = tau * tau;   // fl(tau^2)
    const float l2 = lam * lam;   // fl(lam^2)

    const int tx = lane & 7;      // col-groups: cols tx+8j, j<4
    const int ty = lane >> 3;     // row-groups: rows ty+8i, i<4

    float G[4][4], Pd[4][4];
#pragma unroll
    for (int i = 0; i < 4; ++i)
#pragma unroll
        for (int j = 0; j < 4; ++j) { G[i][j] = 0.0f; Pd[i][j] = 1.0f; }

    // two k-halves, overall k descending 15..8 then 7..0 (recurrence carries)
#pragma unroll
    for (int h = 0; h < 2; ++h) {
        const int kbase = 8 - 8 * h;

        // stage this half: 2 sets x 32 rows x 8 chunks = 512 tasks, 8/lane
#pragma unroll
        for (int it = 0; it < 8; ++it) {
            int task = lane + 64 * it;
            int set = task >> 8;
            int rk = task & 255;
            int r = rk & 31, kk = rk >> 5;
            int base = ((set ? col0 : row0) + r) * D + (kbase + kk) * 3;
            float x0 = vct[base + 0];
            float x1 = vct[base + 1];
            float x2 = vct[base + 2];
            float q0 = x0 * x0, q1 = x1 * x1, q2 = x2 * x2;
            asm volatile("" : "+v"(q0), "+v"(q1), "+v"(q2));
            float s02 = q0 + q2;
            asm volatile("" : "+v"(s02));
            float s = s02 + q1;               // (q0+q2)+q1, pinned plain
            SB[set * 256 + kk * TILE + r] = make_float4(x0, x1, x2, s);
        }
        __syncthreads();   // 1-wave fence (cheap): staging -> compute

#pragma unroll
        for (int kk = 7; kk >= 0; --kk) {
            float4 a[4], b[4];
#pragma unroll
            for (int i = 0; i < 4; ++i) a[i] = SB[kk * TILE + ty + 8 * i];
#pragma unroll
            for (int j = 0; j < 4; ++j) b[j] = SB[256 + kk * TILE + tx + 8 * j];
#pragma unroll
            for (int i = 0; i < 4; ++i)
#pragma unroll
                for (int j = 0; j < 4; ++j) {
                    // FROZEN distance path
                    float g = __builtin_fmaf(a[i].z, b[j].z,
                              __builtin_fmaf(a[i].y, b[j].y, a[i].x * b[j].x));
                    float t1 = a[i].w + b[j].w;
                    float d2 = __builtin_fmaf(-2.0f, g, t1);
                    float dist = __builtin_amdgcn_sqrtf(fmaxf(d2, 0.0f));
                    float ip  = 1.0f - dist;
                    float den = 1.0f - t2 * ip;
                    G[i][j]  = l2 * (Pd[i][j] + G[i][j]);
                    Pd[i][j] = Pd[i][j] * den;
                }
        }
        __syncthreads();   // compute -> next-half staging (buffer reuse)
    }

    // finalize
    float val[4][4];
#pragma unroll
    for (int i = 0; i < 4; ++i)
#pragma unroll
        for (int j = 0; j < 4; ++j)
            val[i][j] = 1.0f + G[i][j] * __builtin_amdgcn_rcpf(Pd[i][j]);

    // direct store (lanes vary tx -> 8-col segments x 8 rows per instr)
#pragma unroll
    for (int i = 0; i < 4; ++i) {
        int r = ty + 8 * i;
#pragma unroll
        for (int j = 0; j < 4; ++j)
            out[(size_t)(row0 + r) * N + (col0 + tx + 8 * j)] = val[i][j];
    }

    if (bx != by) {
        // transpose through LDS (SB dead): T[c*ST + r], 2-way alias max
#pragma unroll
        for (int i = 0; i < 4; ++i)
#pragma unroll
            for (int j = 0; j < 4; ++j)
                T[(tx + 8 * j) * ST + (ty + 8 * i)] = val[i][j];
        __syncthreads();   // 1-wave fence: T writes -> T reads
#pragma unroll
        for (int i = 0; i < 4; ++i) {
            int rr = ty + 8 * i;
#pragma unroll
            for (int j = 0; j < 4; ++j) {
                int cc = tx + 8 * j;
                out[(size_t)(col0 + rr) * N + (row0 + cc)] = T[rr * ST + cc];
            }
        }
    }
}

extern "C" void kernel_launch(void* const* d_in, const int* in_sizes, int n_in,
                              void* d_out, int out_size, void* d_ws, size_t ws_size,
                              hipStream_t stream) {
    const float* vct    = (const float*)d_in[0];
    const float* posnum = (const float*)d_in[1];
    float* out          = (float*)d_out;

    volt_tri<<<NBLK, 64, 0, stream>>>(vct, posnum, out);
}